// Round 2
// baseline (980.723 us; speedup 1.0000x reference)
//
#include <hip/hip_runtime.h>

// ---------------------------------------------------------------------------
// HeteroRGCN: 3x (RGCNConv mean-per-relation + ReLU + BN(eval)) + Linear
// fp32 everywhere (round 1 resubmit: correctness + baseline profile).
// Strategy: transform-first. h_r = x @ W_r for all r (dense GEMM), then one
// edge pass: acc[dst] += h_r[src] * inv_cnt[dst][r]. inv_cnt built once/call.
// ---------------------------------------------------------------------------

#define R_REL 8

// Tiled fp32 GEMM: C[64 x 64] tile per block. A [n x K] row-major,
// B = Wbase + (base_rel + blockIdx.y) * w_stride, [K x 64] row-major.
// out tile at rows blockIdx.x*64, cols blockIdx.y*64 (ld = ldo).
// If bias != null, adds bias[col].
__global__ __launch_bounds__(256)
void gemm_kernel(const float* __restrict__ A, int n, int K,
                 const float* __restrict__ Wbase, size_t w_stride, int base_rel,
                 const float* __restrict__ bias,
                 float* __restrict__ out, int ldo)
{
    __shared__ float Ast[64][68];   // transposed: Ast[k][r], stride 68 (bank-safe)
    __shared__ float Bs[64][64];

    const int row0 = blockIdx.x * 64;
    const float* B = Wbase + (size_t)(base_rel + blockIdx.y) * w_stride;
    const int colbase = blockIdx.y * 64;

    const int tx = threadIdx.x & 15;   // output col group (4 cols)
    const int ty = threadIdx.x >> 4;   // output row group (4 rows)

    float acc[4][4] = {};

    for (int kb = 0; kb < K; kb += 64) {
        // load B tile (64 x 64)
        for (int i = threadIdx.x; i < 64 * 16; i += 256) {
            int k = i >> 4, c4 = (i & 15) << 2;
            *(float4*)&Bs[k][c4] = *(const float4*)&B[(size_t)(kb + k) * 64 + c4];
        }
        // load A tile (64 rows x 64 k), store transposed
        for (int i = threadIdx.x; i < 64 * 16; i += 256) {
            int r = i >> 4, k4 = (i & 15) << 2;
            float4 v = make_float4(0.f, 0.f, 0.f, 0.f);
            if (row0 + r < n)
                v = *(const float4*)&A[(size_t)(row0 + r) * K + kb + k4];
            Ast[k4 + 0][r] = v.x;
            Ast[k4 + 1][r] = v.y;
            Ast[k4 + 2][r] = v.z;
            Ast[k4 + 3][r] = v.w;
        }
        __syncthreads();

        #pragma unroll 8
        for (int k = 0; k < 64; ++k) {
            float4 a = *(const float4*)&Ast[k][ty << 2];
            float4 b = *(const float4*)&Bs[k][tx << 2];
            acc[0][0] += a.x * b.x; acc[0][1] += a.x * b.y; acc[0][2] += a.x * b.z; acc[0][3] += a.x * b.w;
            acc[1][0] += a.y * b.x; acc[1][1] += a.y * b.y; acc[1][2] += a.y * b.z; acc[1][3] += a.y * b.w;
            acc[2][0] += a.z * b.x; acc[2][1] += a.z * b.y; acc[2][2] += a.z * b.z; acc[2][3] += a.z * b.w;
            acc[3][0] += a.w * b.x; acc[3][1] += a.w * b.y; acc[3][2] += a.w * b.z; acc[3][3] += a.w * b.w;
        }
        __syncthreads();
    }

    float bv[4] = {0.f, 0.f, 0.f, 0.f};
    if (bias) {
        bv[0] = bias[(tx << 2) + 0];
        bv[1] = bias[(tx << 2) + 1];
        bv[2] = bias[(tx << 2) + 2];
        bv[3] = bias[(tx << 2) + 3];
    }
    #pragma unroll
    for (int i = 0; i < 4; ++i) {
        int r = row0 + (ty << 2) + i;
        if (r < n) {
            float4 o;
            o.x = acc[i][0] + bv[0];
            o.y = acc[i][1] + bv[1];
            o.z = acc[i][2] + bv[2];
            o.w = acc[i][3] + bv[3];
            *(float4*)&out[(size_t)r * ldo + colbase + (tx << 2)] = o;
        }
    }
}

// count in-edges per (dst, relation)
__global__ void count_kernel(const int* __restrict__ ei, const int* __restrict__ et,
                             int* __restrict__ cnt, int E)
{
    int e = blockIdx.x * 256 + threadIdx.x;
    if (e < E) atomicAdd(&cnt[(size_t)ei[E + e] * R_REL + et[e]], 1);
}

// in-place int count -> float 1/max(cnt,1)
__global__ void inv_kernel(float* __restrict__ buf, int n)
{
    int i = blockIdx.x * 256 + threadIdx.x;
    if (i < n) {
        int c = ((const int*)buf)[i];
        buf[i] = 1.0f / (float)(c > 1 ? c : 1);
    }
}

// edge aggregation: acc[dst][j] += H[src][(r-r0)*64 + j] * inv[dst][r]
__global__ __launch_bounds__(256)
void agg_kernel(const int* __restrict__ ei, const int* __restrict__ et,
                const float* __restrict__ H, const float* __restrict__ inv,
                float* __restrict__ acc, int E, int r0, int nch)
{
    const int lane = threadIdx.x & 63;
    const int waveSlot = (blockIdx.x * 256 + threadIdx.x) >> 6;
    const int nSlots = (gridDim.x * 256) >> 6;
    const int ldh = nch << 6;
    for (int e = waveSlot; e < E; e += nSlots) {
        int r = et[e];
        if (r < r0 || r >= r0 + nch) continue;
        int s = ei[e];
        int d = ei[E + e];
        float v = H[(size_t)s * ldh + ((r - r0) << 6) + lane] * inv[(size_t)d * R_REL + r];
        atomicAdd(&acc[(size_t)d * 64 + lane], v);
    }
}

// relu -> eval-BN, acc -> xout  (n4 = N*16 float4s)
__global__ void epi_kernel(const float* __restrict__ acc,
                           const float* __restrict__ g, const float* __restrict__ b,
                           const float* __restrict__ rm, const float* __restrict__ rv,
                           float* __restrict__ xout, int n4)
{
    int i = blockIdx.x * 256 + threadIdx.x;
    if (i >= n4) return;
    float4 v = ((const float4*)acc)[i];
    int c = (i & 15) << 2;
    float vv[4] = {v.x, v.y, v.z, v.w};
    #pragma unroll
    for (int j = 0; j < 4; ++j) {
        float t = vv[j] > 0.f ? vv[j] : 0.f;
        vv[j] = (t - rm[c + j]) * rsqrtf(rv[c + j] + 1e-5f) * g[c + j] + b[c + j];
    }
    ((float4*)xout)[i] = make_float4(vv[0], vv[1], vv[2], vv[3]);
}

// final linear: out[n][c] = sum_k h[n][k] * Wl[k][c] + bl[c]   (C = 16)
__global__ __launch_bounds__(256)
void lin_kernel(const float* __restrict__ h, const float* __restrict__ Wl,
                const float* __restrict__ bl, float* __restrict__ out, int N)
{
    __shared__ float w[64 * 16];
    __shared__ float bb[16];
    for (int i = threadIdx.x; i < 64 * 16; i += 256) w[i] = Wl[i];
    if (threadIdx.x < 16) bb[threadIdx.x] = bl[threadIdx.x];
    __syncthreads();

    int idx = blockIdx.x * 256 + threadIdx.x;
    if (idx >= N * 16) return;
    int node = idx >> 4, c = idx & 15;
    float s = bb[c];
    const float* hr = h + (size_t)node * 64;
    #pragma unroll 16
    for (int k = 0; k < 64; ++k) s += hr[k] * w[k * 16 + c];
    out[idx] = s;
}

extern "C" void kernel_launch(void* const* d_in, const int* in_sizes, int n_in,
                              void* d_out, int out_size, void* d_ws, size_t ws_size,
                              hipStream_t stream)
{
    const float* x  = (const float*)d_in[0];
    const int*   ei = (const int*)d_in[1];
    const int*   et = (const int*)d_in[2];
    const float* W[3]    = {(const float*)d_in[3], (const float*)d_in[6], (const float*)d_in[9]};
    const float* root[3] = {(const float*)d_in[4], (const float*)d_in[7], (const float*)d_in[10]};
    const float* bias[3] = {(const float*)d_in[5], (const float*)d_in[8], (const float*)d_in[11]};
    const float* gamma[3] = {(const float*)d_in[12], (const float*)d_in[16], (const float*)d_in[20]};
    const float* beta[3]  = {(const float*)d_in[13], (const float*)d_in[17], (const float*)d_in[21]};
    const float* rm[3]    = {(const float*)d_in[14], (const float*)d_in[18], (const float*)d_in[22]};
    const float* rv[3]    = {(const float*)d_in[15], (const float*)d_in[19], (const float*)d_in[23]};
    const float* Wl = (const float*)d_in[24];
    const float* bl = (const float*)d_in[25];

    const int N = in_sizes[0] / 128;
    const int E = in_sizes[2];

    // pick relation chunk to fit workspace
    int CH = 8;
    while (CH > 1 && (size_t)N * (size_t)(R_REL + CH * 64 + 64 + 64) * 4 > ws_size) CH >>= 1;

    float* wsf  = (float*)d_ws;
    float* inv  = wsf;                          // N*8   (int counts, then float inv)
    float* Hbuf = inv + (size_t)N * R_REL;      // N*CH*64
    float* accb = Hbuf + (size_t)N * CH * 64;   // N*64
    float* xb   = accb + (size_t)N * 64;        // N*64

    // per-(dst, relation) inverse counts (edge structure is call-invariant,
    // but ws is re-poisoned each call, so rebuild every call)
    hipMemsetAsync(inv, 0, (size_t)N * R_REL * 4, stream);
    count_kernel<<<(E + 255) / 256, 256, 0, stream>>>(ei, et, (int*)inv, E);
    inv_kernel<<<(N * R_REL + 255) / 256, 256, 0, stream>>>(inv, N * R_REL);

    const int gx = (N + 63) / 64;
    const float* cur = x;
    for (int layer = 0; layer < 3; ++layer) {
        const int K = (layer == 0) ? 128 : 64;
        // acc = cur @ root + bias
        gemm_kernel<<<dim3(gx, 1), 256, 0, stream>>>(
            cur, N, K, root[layer], 0, 0, bias[layer], accb, 64);
        // per-relation transforms + edge aggregation
        for (int r0 = 0; r0 < R_REL; r0 += CH) {
            gemm_kernel<<<dim3(gx, CH), 256, 0, stream>>>(
                cur, N, K, W[layer], (size_t)K * 64, r0, nullptr, Hbuf, CH * 64);
            agg_kernel<<<4096, 256, 0, stream>>>(ei, et, Hbuf, inv, accb, E, r0, CH);
        }
        // relu + BN -> xb
        epi_kernel<<<(N * 16 + 255) / 256, 256, 0, stream>>>(
            accb, gamma[layer], beta[layer], rm[layer], rv[layer], xb, N * 16);
        cur = xb;
    }

    lin_kernel<<<(N * 16 + 255) / 256, 256, 0, stream>>>(cur, Wl, bl, (float*)d_out, N);
}

// Round 3
// 736.975 us; speedup vs baseline: 1.3307x; 1.3307x over previous
//
#include <hip/hip_runtime.h>

// ---------------------------------------------------------------------------
// HeteroRGCN: 3x (RGCNConv mean-per-relation + ReLU + BN(eval)) + Linear
// Round 2: replace atomic aggregation with per-call dst-CSR + one-wave-per-dst
// segmented reduction (no atomics in the hot loop), fuse ReLU+BN epilogue.
// ---------------------------------------------------------------------------

#define R_REL 8

// Tiled fp32 GEMM: C[64 x 64] tile per block. A [n x K] row-major,
// B = Wbase + (base_rel + blockIdx.y) * w_stride, [K x 64] row-major.
__global__ __launch_bounds__(256)
void gemm_kernel(const float* __restrict__ A, int n, int K,
                 const float* __restrict__ Wbase, size_t w_stride, int base_rel,
                 const float* __restrict__ bias,
                 float* __restrict__ out, int ldo)
{
    __shared__ float Ast[64][68];
    __shared__ float Bs[64][64];

    const int row0 = blockIdx.x * 64;
    const float* B = Wbase + (size_t)(base_rel + blockIdx.y) * w_stride;
    const int colbase = blockIdx.y * 64;

    const int tx = threadIdx.x & 15;
    const int ty = threadIdx.x >> 4;

    float acc[4][4] = {};

    for (int kb = 0; kb < K; kb += 64) {
        for (int i = threadIdx.x; i < 64 * 16; i += 256) {
            int k = i >> 4, c4 = (i & 15) << 2;
            *(float4*)&Bs[k][c4] = *(const float4*)&B[(size_t)(kb + k) * 64 + c4];
        }
        for (int i = threadIdx.x; i < 64 * 16; i += 256) {
            int r = i >> 4, k4 = (i & 15) << 2;
            float4 v = make_float4(0.f, 0.f, 0.f, 0.f);
            if (row0 + r < n)
                v = *(const float4*)&A[(size_t)(row0 + r) * K + kb + k4];
            Ast[k4 + 0][r] = v.x;
            Ast[k4 + 1][r] = v.y;
            Ast[k4 + 2][r] = v.z;
            Ast[k4 + 3][r] = v.w;
        }
        __syncthreads();

        #pragma unroll 8
        for (int k = 0; k < 64; ++k) {
            float4 a = *(const float4*)&Ast[k][ty << 2];
            float4 b = *(const float4*)&Bs[k][tx << 2];
            acc[0][0] += a.x * b.x; acc[0][1] += a.x * b.y; acc[0][2] += a.x * b.z; acc[0][3] += a.x * b.w;
            acc[1][0] += a.y * b.x; acc[1][1] += a.y * b.y; acc[1][2] += a.y * b.z; acc[1][3] += a.y * b.w;
            acc[2][0] += a.z * b.x; acc[2][1] += a.z * b.y; acc[2][2] += a.z * b.z; acc[2][3] += a.z * b.w;
            acc[3][0] += a.w * b.x; acc[3][1] += a.w * b.y; acc[3][2] += a.w * b.z; acc[3][3] += a.w * b.w;
        }
        __syncthreads();
    }

    float bv[4] = {0.f, 0.f, 0.f, 0.f};
    if (bias) {
        bv[0] = bias[(tx << 2) + 0];
        bv[1] = bias[(tx << 2) + 1];
        bv[2] = bias[(tx << 2) + 2];
        bv[3] = bias[(tx << 2) + 3];
    }
    #pragma unroll
    for (int i = 0; i < 4; ++i) {
        int r = row0 + (ty << 2) + i;
        if (r < n) {
            float4 o;
            o.x = acc[i][0] + bv[0];
            o.y = acc[i][1] + bv[1];
            o.z = acc[i][2] + bv[2];
            o.w = acc[i][3] + bv[3];
            *(float4*)&out[(size_t)r * ldo + colbase + (tx << 2)] = o;
        }
    }
}

// count in-edges per (dst, relation)
__global__ void count_kernel(const int* __restrict__ ei, const int* __restrict__ et,
                             int* __restrict__ cnt, int E)
{
    int e = blockIdx.x * 256 + threadIdx.x;
    if (e < E) atomicAdd(&cnt[(size_t)ei[E + e] * R_REL + et[e]], 1);
}

// per dst: counts -> inv (in place) + total degree
__global__ void invdeg_kernel(float* __restrict__ inv, int* __restrict__ deg, int N)
{
    int i = blockIdx.x * 256 + threadIdx.x;
    if (i >= N) return;
    const int* c = (const int*)inv;
    int tot = 0;
    float out[R_REL];
    #pragma unroll
    for (int r = 0; r < R_REL; ++r) {
        int cc = c[i * R_REL + r];
        tot += cc;
        out[r] = 1.0f / (float)(cc > 1 ? cc : 1);
    }
    #pragma unroll
    for (int r = 0; r < R_REL; ++r) inv[i * R_REL + r] = out[r];
    deg[i] = tot;
}

// hierarchical exclusive scan of deg[N] -> offs[N]; partials per block
__global__ void scan1_kernel(const int* __restrict__ deg, int* __restrict__ offs,
                             int* __restrict__ partials, int N)
{
    __shared__ int sm[256];
    int i = blockIdx.x * 256 + threadIdx.x;
    int c = (i < N) ? deg[i] : 0;
    sm[threadIdx.x] = c;
    __syncthreads();
    for (int off = 1; off < 256; off <<= 1) {
        int t = (threadIdx.x >= off) ? sm[threadIdx.x - off] : 0;
        __syncthreads();
        sm[threadIdx.x] += t;
        __syncthreads();
    }
    if (i < N) offs[i] = sm[threadIdx.x] - c;   // chunk-local exclusive
    if (threadIdx.x == 255) partials[blockIdx.x] = sm[255];
}

// single-block exclusive scan of partials[P] (loop-carried)
__global__ void scan2_kernel(int* __restrict__ partials, int P)
{
    __shared__ int sm[256];
    __shared__ int carry;
    if (threadIdx.x == 0) carry = 0;
    __syncthreads();
    for (int base = 0; base < P; base += 256) {
        int i = base + threadIdx.x;
        int c = (i < P) ? partials[i] : 0;
        sm[threadIdx.x] = c;
        __syncthreads();
        for (int off = 1; off < 256; off <<= 1) {
            int t = (threadIdx.x >= off) ? sm[threadIdx.x - off] : 0;
            __syncthreads();
            sm[threadIdx.x] += t;
            __syncthreads();
        }
        int incl = sm[threadIdx.x];
        int cold = carry;
        if (i < P) partials[i] = incl - c + cold;
        __syncthreads();
        if (threadIdx.x == 0) carry = cold + sm[255];
        __syncthreads();
    }
}

__global__ void scan3_kernel(int* __restrict__ offs, const int* __restrict__ partials, int N)
{
    int i = blockIdx.x * 256 + threadIdx.x;
    if (i < N) offs[i] += partials[blockIdx.x];
}

// scatter edges into CSR slots: packed = src | (rel << 24)
__global__ void fill_kernel(const int* __restrict__ ei, const int* __restrict__ et,
                            const int* __restrict__ offs, int* __restrict__ cursor,
                            int* __restrict__ packed, int E)
{
    int e = blockIdx.x * 256 + threadIdx.x;
    if (e >= E) return;
    int d = ei[E + e];
    int pos = offs[d] + atomicAdd(&cursor[d], 1);
    packed[pos] = ei[e] | (et[e] << 24);
}

// one wave per dst: acc_row += sum over in-edges H[src]*inv[dst][r];
// on last chunk: ReLU + BN(eval) -> xout, else write back accb.
__global__ __launch_bounds__(256)
void agg2_kernel(const int* __restrict__ packed, const int* __restrict__ offs,
                 const int* __restrict__ deg,
                 const float* __restrict__ H, const float* __restrict__ inv,
                 float* __restrict__ accb,
                 const float* __restrict__ g, const float* __restrict__ b,
                 const float* __restrict__ rm, const float* __restrict__ rv,
                 float* __restrict__ xout, int N, int r0, int nch, int last)
{
    const int lane = threadIdx.x & 63;
    const int d = (blockIdx.x * 256 + threadIdx.x) >> 6;
    if (d >= N) return;

    const int n0 = offs[d];
    const int dg = deg[d];
    const int ldh = nch << 6;
    float s = accb[(size_t)d * 64 + lane];
    const float* invd = &inv[(size_t)d * R_REL];

    for (int k = 0; k < dg; ++k) {
        int p = packed[n0 + k];
        int r = p >> 24;
        if (r < r0 || r >= r0 + nch) continue;
        int src = p & 0xFFFFFF;
        s += H[(size_t)src * ldh + ((r - r0) << 6) + lane] * invd[r];
    }

    if (last) {
        float t = s > 0.f ? s : 0.f;
        xout[(size_t)d * 64 + lane] =
            (t - rm[lane]) * rsqrtf(rv[lane] + 1e-5f) * g[lane] + b[lane];
    } else {
        accb[(size_t)d * 64 + lane] = s;
    }
}

// final linear: out[n][c] = sum_k h[n][k] * Wl[k][c] + bl[c]   (C = 16)
__global__ __launch_bounds__(256)
void lin_kernel(const float* __restrict__ h, const float* __restrict__ Wl,
                const float* __restrict__ bl, float* __restrict__ out, int N)
{
    __shared__ float w[64 * 16];
    __shared__ float bb[16];
    for (int i = threadIdx.x; i < 64 * 16; i += 256) w[i] = Wl[i];
    if (threadIdx.x < 16) bb[threadIdx.x] = bl[threadIdx.x];
    __syncthreads();

    int idx = blockIdx.x * 256 + threadIdx.x;
    if (idx >= N * 16) return;
    int node = idx >> 4, c = idx & 15;
    float s = bb[c];
    const float* hr = h + (size_t)node * 64;
    #pragma unroll 16
    for (int k = 0; k < 64; ++k) s += hr[k] * w[k * 16 + c];
    out[idx] = s;
}

extern "C" void kernel_launch(void* const* d_in, const int* in_sizes, int n_in,
                              void* d_out, int out_size, void* d_ws, size_t ws_size,
                              hipStream_t stream)
{
    const float* x  = (const float*)d_in[0];
    const int*   ei = (const int*)d_in[1];
    const int*   et = (const int*)d_in[2];
    const float* W[3]    = {(const float*)d_in[3], (const float*)d_in[6], (const float*)d_in[9]};
    const float* root[3] = {(const float*)d_in[4], (const float*)d_in[7], (const float*)d_in[10]};
    const float* bias[3] = {(const float*)d_in[5], (const float*)d_in[8], (const float*)d_in[11]};
    const float* gamma[3] = {(const float*)d_in[12], (const float*)d_in[16], (const float*)d_in[20]};
    const float* beta[3]  = {(const float*)d_in[13], (const float*)d_in[17], (const float*)d_in[21]};
    const float* rm[3]    = {(const float*)d_in[14], (const float*)d_in[18], (const float*)d_in[22]};
    const float* rv[3]    = {(const float*)d_in[15], (const float*)d_in[19], (const float*)d_in[23]};
    const float* Wl = (const float*)d_in[24];
    const float* bl = (const float*)d_in[25];

    const int N = in_sizes[0] / 128;
    const int E = in_sizes[2];

    const size_t intBytes = ((size_t)3 * N + E + 512) * 4;
    int CH = 8;
    while (CH > 1 &&
           (size_t)N * (size_t)(R_REL + CH * 64 + 64 + 64) * 4 + intBytes > ws_size)
        CH >>= 1;

    float* wsf  = (float*)d_ws;
    float* inv  = wsf;                          // N*8 (int counts -> float inv)
    float* Hbuf = inv + (size_t)N * R_REL;      // N*CH*64
    float* accb = Hbuf + (size_t)N * CH * 64;   // N*64
    float* xb   = accb + (size_t)N * 64;        // N*64
    int*   offs    = (int*)(xb + (size_t)N * 64);   // N
    int*   deg     = offs + N;                      // N
    int*   cursor  = deg + N;                       // N
    int*   packed  = cursor + N;                    // E
    int*   partials = packed + E;                   // <=512

    const int gxN = (N + 255) / 256;

    // ---- CSR build (per call; ws is re-poisoned every call) ----
    hipMemsetAsync(inv, 0, (size_t)N * R_REL * 4, stream);
    hipMemsetAsync(cursor, 0, (size_t)N * 4, stream);
    count_kernel<<<(E + 255) / 256, 256, 0, stream>>>(ei, et, (int*)inv, E);
    invdeg_kernel<<<gxN, 256, 0, stream>>>(inv, deg, N);
    scan1_kernel<<<gxN, 256, 0, stream>>>(deg, offs, partials, N);
    scan2_kernel<<<1, 256, 0, stream>>>(partials, gxN);
    scan3_kernel<<<gxN, 256, 0, stream>>>(offs, partials, N);
    fill_kernel<<<(E + 255) / 256, 256, 0, stream>>>(ei, et, offs, cursor, packed, E);

    // ---- 3 RGCN layers ----
    const int gx = (N + 63) / 64;
    const int gagg = (N * 64 + 255) / 256;
    const float* cur = x;
    for (int layer = 0; layer < 3; ++layer) {
        const int K = (layer == 0) ? 128 : 64;
        gemm_kernel<<<dim3(gx, 1), 256, 0, stream>>>(
            cur, N, K, root[layer], 0, 0, bias[layer], accb, 64);
        for (int r0 = 0; r0 < R_REL; r0 += CH) {
            gemm_kernel<<<dim3(gx, CH), 256, 0, stream>>>(
                cur, N, K, W[layer], (size_t)K * 64, r0, nullptr, Hbuf, CH * 64);
            int last = (r0 + CH >= R_REL);
            agg2_kernel<<<gagg, 256, 0, stream>>>(
                packed, offs, deg, Hbuf, inv, accb,
                gamma[layer], beta[layer], rm[layer], rv[layer],
                xb, N, r0, CH, last);
        }
        cur = xb;
    }

    lin_kernel<<<(N * 16 + 255) / 256, 256, 0, stream>>>(cur, Wl, bl, (float*)d_out, N);
}

// Round 6
// 565.467 us; speedup vs baseline: 1.7344x; 1.3033x over previous
//
#include <hip/hip_runtime.h>

// ---------------------------------------------------------------------------
// HeteroRGCN: 3x (RGCNConv mean-per-relation + ReLU + BN(eval)) + Linear
// Round 5 (resubmit; infra timeouts r4/r5): bf16 MFMA GEMMs (16x16x32),
// bf16 H/x buffers, CSR agg with precomputed per-edge weights, fused ReLU+BN.
// ---------------------------------------------------------------------------

#define R_REL 8

typedef unsigned short ushort_t;
typedef short short8 __attribute__((ext_vector_type(8)));
typedef float f32x4 __attribute__((ext_vector_type(4)));

#define MFMA(a, b, c) __builtin_amdgcn_mfma_f32_16x16x32_bf16(a, b, c, 0, 0, 0)

static __device__ __forceinline__ unsigned short f2bf(float f) {
    unsigned int u = __float_as_uint(f);
    u = (u + 0x7FFF + ((u >> 16) & 1)) >> 16;   // round-to-nearest-even
    return (unsigned short)u;
}
static __device__ __forceinline__ float bf2f(unsigned short h) {
    return __uint_as_float(((unsigned int)h) << 16);
}

// ---- weight convert + transpose: src f32 [G][K][64] -> dst bf16 [G][64][K]
__global__ void wcvt_kernel(const float* __restrict__ src, ushort_t* __restrict__ dst,
                            int G, int K)
{
    int i = blockIdx.x * 256 + threadIdx.x;
    if (i >= G * K * 64) return;
    int g = i / (K * 64), rem = i % (K * 64), k = rem >> 6, c = rem & 63;
    dst[(size_t)g * 64 * K + (size_t)c * K + k] = f2bf(src[i]);
}

// ---- input convert: f32 -> bf16 (4 elems/thread)
__global__ void xcvt_kernel(const float* __restrict__ src, ushort_t* __restrict__ dst, int n4)
{
    int i = blockIdx.x * 256 + threadIdx.x;
    if (i >= n4) return;
    float4 v = ((const float4*)src)[i];
    ushort_t t[4] = {f2bf(v.x), f2bf(v.y), f2bf(v.z), f2bf(v.w)};
    *(uint2*)&dst[(size_t)i * 4] = *(const uint2*)t;
}

// ---- MFMA GEMM: A [n x K] bf16 row-major; blockIdx.y<8: B=WT[y] ([64][K] bf16,
// pre-transposed) -> H bf16 (ld 512, colbase y*64); y==8: B=RT -> accb f32 + bias.
__global__ __launch_bounds__(256)
void mgemm_kernel(const ushort_t* __restrict__ A, int n, int K,
                  const ushort_t* __restrict__ WT, const ushort_t* __restrict__ RT,
                  const float* __restrict__ bias,
                  ushort_t* __restrict__ H, float* __restrict__ accb)
{
    __shared__ ushort_t As[64][136];   // row stride 272B -> 2-way (free) on ds_read_b128
    __shared__ ushort_t Bs[64][136];

    const int row0 = blockIdx.x * 64;
    const int yr = blockIdx.y;
    const ushort_t* Bsrc = (yr < R_REL) ? (WT + (size_t)yr * 64 * K) : RT;

    const int tid = threadIdx.x;
    const int KB = K >> 3;   // 16B chunks per row

    for (int i = tid; i < 64 * KB; i += 256) {
        int r = i / KB, k8 = (i % KB) << 3;
        *(uint4*)&Bs[r][k8] = *(const uint4*)&Bsrc[(size_t)r * K + k8];
        uint4 av = make_uint4(0u, 0u, 0u, 0u);
        if (row0 + r < n) av = *(const uint4*)&A[(size_t)(row0 + r) * K + k8];
        *(uint4*)&As[r][k8] = av;
    }
    __syncthreads();

    const int wid  = tid >> 6;
    const int lane = tid & 63;
    const int wr = (wid >> 1) * 32;     // wave row offset in 64x64 tile
    const int wc = (wid & 1) * 32;      // wave col offset
    const int fr = lane & 15;
    const int kg = (lane >> 4) << 3;    // k sub-offset 0/8/16/24

    f32x4 acc[2][2] = {};
    for (int k0 = 0; k0 < K; k0 += 32) {
        short8 a0 = *(const short8*)&As[wr + fr     ][k0 + kg];
        short8 a1 = *(const short8*)&As[wr + 16 + fr][k0 + kg];
        short8 b0 = *(const short8*)&Bs[wc + fr     ][k0 + kg];
        short8 b1 = *(const short8*)&Bs[wc + 16 + fr][k0 + kg];
        acc[0][0] = MFMA(a0, b0, acc[0][0]);
        acc[0][1] = MFMA(a0, b1, acc[0][1]);
        acc[1][0] = MFMA(a1, b0, acc[1][0]);
        acc[1][1] = MFMA(a1, b1, acc[1][1]);
    }
    __syncthreads();   // done reading As/Bs; reuse As as f32 staging

    float* Ct = (float*)As;            // [64][68] f32 (exactly fits As)
    const int rbase = (lane >> 4) << 2;
    #pragma unroll
    for (int m = 0; m < 2; ++m)
        #pragma unroll
        for (int nn = 0; nn < 2; ++nn)
            #pragma unroll
            for (int j = 0; j < 4; ++j)
                Ct[(wr + m * 16 + rbase + j) * 68 + wc + nn * 16 + fr] = acc[m][nn][j];
    __syncthreads();

    if (yr < R_REL) {
        const int cb = yr << 6;
        for (int i = tid; i < 64 * 8; i += 256) {
            int r = i >> 3, c8 = (i & 7) << 3;
            if (row0 + r < n) {
                ushort_t t[8];
                #pragma unroll
                for (int j = 0; j < 8; ++j) t[j] = f2bf(Ct[r * 68 + c8 + j]);
                *(uint4*)&H[(size_t)(row0 + r) * 512 + cb + c8] = *(const uint4*)t;
            }
        }
    } else {
        for (int i = tid; i < 64 * 16; i += 256) {
            int r = i >> 4, c4 = (i & 15) << 2;
            if (row0 + r < n) {
                float4 o;
                o.x = Ct[r * 68 + c4 + 0] + bias[c4 + 0];
                o.y = Ct[r * 68 + c4 + 1] + bias[c4 + 1];
                o.z = Ct[r * 68 + c4 + 2] + bias[c4 + 2];
                o.w = Ct[r * 68 + c4 + 3] + bias[c4 + 3];
                *(float4*)&accb[(size_t)(row0 + r) * 64 + c4] = o;
            }
        }
    }
}

// ---- CSR build -------------------------------------------------------------
__global__ void count_kernel(const int* __restrict__ ei, const int* __restrict__ et,
                             int* __restrict__ cnt, int E)
{
    int e = blockIdx.x * 256 + threadIdx.x;
    if (e < E) atomicAdd(&cnt[(size_t)ei[E + e] * R_REL + et[e]], 1);
}

__global__ void invdeg_kernel(float* __restrict__ inv, int* __restrict__ deg, int N)
{
    int i = blockIdx.x * 256 + threadIdx.x;
    if (i >= N) return;
    const int* c = (const int*)inv;
    int tot = 0;
    float out[R_REL];
    #pragma unroll
    for (int r = 0; r < R_REL; ++r) {
        int cc = c[i * R_REL + r];
        tot += cc;
        out[r] = 1.0f / (float)(cc > 1 ? cc : 1);
    }
    #pragma unroll
    for (int r = 0; r < R_REL; ++r) inv[i * R_REL + r] = out[r];
    deg[i] = tot;
}

__global__ void scan1_kernel(const int* __restrict__ deg, int* __restrict__ offs,
                             int* __restrict__ partials, int N)
{
    __shared__ int sm[256];
    int i = blockIdx.x * 256 + threadIdx.x;
    int c = (i < N) ? deg[i] : 0;
    sm[threadIdx.x] = c;
    __syncthreads();
    for (int off = 1; off < 256; off <<= 1) {
        int t = (threadIdx.x >= off) ? sm[threadIdx.x - off] : 0;
        __syncthreads();
        sm[threadIdx.x] += t;
        __syncthreads();
    }
    if (i < N) offs[i] = sm[threadIdx.x] - c;
    if (threadIdx.x == 255) partials[blockIdx.x] = sm[255];
}

__global__ void scan2_kernel(int* __restrict__ partials, int P)
{
    __shared__ int sm[256];
    __shared__ int carry;
    if (threadIdx.x == 0) carry = 0;
    __syncthreads();
    for (int base = 0; base < P; base += 256) {
        int i = base + threadIdx.x;
        int c = (i < P) ? partials[i] : 0;
        sm[threadIdx.x] = c;
        __syncthreads();
        for (int off = 1; off < 256; off <<= 1) {
            int t = (threadIdx.x >= off) ? sm[threadIdx.x - off] : 0;
            __syncthreads();
            sm[threadIdx.x] += t;
            __syncthreads();
        }
        int incl = sm[threadIdx.x];
        int cold = carry;
        if (i < P) partials[i] = incl - c + cold;
        __syncthreads();
        if (threadIdx.x == 0) carry = cold + sm[255];
        __syncthreads();
    }
}

__global__ void scan3_kernel(int* __restrict__ offs, const int* __restrict__ partials, int N)
{
    int i = blockIdx.x * 256 + threadIdx.x;
    if (i < N) offs[i] += partials[blockIdx.x];
}

// scatter: packed[pos] = src*512 + r*64 (direct bf16-element offset into H),
// pw[pos] = 1/cnt(dst,rel)
__global__ void fill2_kernel(const int* __restrict__ ei, const int* __restrict__ et,
                             const int* __restrict__ offs, int* __restrict__ cursor,
                             const float* __restrict__ inv,
                             int* __restrict__ packed, float* __restrict__ pw, int E)
{
    int e = blockIdx.x * 256 + threadIdx.x;
    if (e >= E) return;
    int d = ei[E + e];
    int r = et[e];
    int pos = offs[d] + atomicAdd(&cursor[d], 1);
    packed[pos] = ei[e] * 512 + r * 64;
    pw[pos] = inv[(size_t)d * R_REL + r];
}

// ---- one wave per dst: s = accb_row + sum_e H[packed + lane]*pw;
// ReLU+BN -> xout (bf16)
__global__ __launch_bounds__(256)
void agg2_kernel(const int* __restrict__ packed, const float* __restrict__ pw,
                 const int* __restrict__ offs, const int* __restrict__ deg,
                 const ushort_t* __restrict__ H, const float* __restrict__ accb,
                 const float* __restrict__ g, const float* __restrict__ b,
                 const float* __restrict__ rm, const float* __restrict__ rv,
                 ushort_t* __restrict__ xout, int N)
{
    const int lane = threadIdx.x & 63;
    const int d = (blockIdx.x * 256 + threadIdx.x) >> 6;
    if (d >= N) return;

    const int n0 = offs[d];
    const int dg = deg[d];
    float s = accb[(size_t)d * 64 + lane];

    for (int k = 0; k < dg; ++k) {
        int hoff = packed[n0 + k];
        float wgt = pw[n0 + k];
        s += bf2f(H[(size_t)hoff + lane]) * wgt;
    }

    float t = s > 0.f ? s : 0.f;
    float o = (t - rm[lane]) * rsqrtf(rv[lane] + 1e-5f) * g[lane] + b[lane];
    xout[(size_t)d * 64 + lane] = f2bf(o);
}

// ---- final linear: out[n][c] = sum_k h[n][k]*Wl[k][c] + bl[c]   (C=16)
__global__ __launch_bounds__(256)
void lin_kernel(const ushort_t* __restrict__ h, const float* __restrict__ Wl,
                const float* __restrict__ bl, float* __restrict__ out, int N)
{
    __shared__ float w[64 * 16];
    __shared__ float bb[16];
    for (int i = threadIdx.x; i < 64 * 16; i += 256) w[i] = Wl[i];
    if (threadIdx.x < 16) bb[threadIdx.x] = bl[threadIdx.x];
    __syncthreads();

    int idx = blockIdx.x * 256 + threadIdx.x;
    if (idx >= N * 16) return;
    int node = idx >> 4, c = idx & 15;
    float s = bb[c];
    const ushort_t* hr = h + (size_t)node * 64;
    #pragma unroll 16
    for (int k = 0; k < 64; ++k) s += bf2f(hr[k]) * w[k * 16 + c];
    out[idx] = s;
}

extern "C" void kernel_launch(void* const* d_in, const int* in_sizes, int n_in,
                              void* d_out, int out_size, void* d_ws, size_t ws_size,
                              hipStream_t stream)
{
    const float* x  = (const float*)d_in[0];
    const int*   ei = (const int*)d_in[1];
    const int*   et = (const int*)d_in[2];
    const float* W[3]    = {(const float*)d_in[3], (const float*)d_in[6], (const float*)d_in[9]};
    const float* root[3] = {(const float*)d_in[4], (const float*)d_in[7], (const float*)d_in[10]};
    const float* bias[3] = {(const float*)d_in[5], (const float*)d_in[8], (const float*)d_in[11]};
    const float* gamma[3] = {(const float*)d_in[12], (const float*)d_in[16], (const float*)d_in[20]};
    const float* beta[3]  = {(const float*)d_in[13], (const float*)d_in[17], (const float*)d_in[21]};
    const float* rm[3]    = {(const float*)d_in[14], (const float*)d_in[18], (const float*)d_in[22]};
    const float* rv[3]    = {(const float*)d_in[15], (const float*)d_in[19], (const float*)d_in[23]};
    const float* Wl = (const float*)d_in[24];
    const float* bl = (const float*)d_in[25];

    const int N = in_sizes[0] / 128;
    const int E = in_sizes[2];
    const int K1 = 128;

    // ---- workspace layout (all 16B aligned) ----
    char* p = (char*)d_ws;
    float*   inv  = (float*)p;    p += (size_t)N * R_REL * 4;
    ushort_t* Hbuf = (ushort_t*)p; p += (size_t)N * 512 * 2;
    float*   accb = (float*)p;    p += (size_t)N * 64 * 4;
    ushort_t* xb  = (ushort_t*)p; p += (size_t)N * 64 * 2;
    ushort_t* x16 = (ushort_t*)p; p += (size_t)N * K1 * 2;
    ushort_t* wt0 = (ushort_t*)p; p += (size_t)R_REL * 64 * K1 * 2;
    ushort_t* wt1 = (ushort_t*)p; p += (size_t)R_REL * 64 * 64 * 2;
    ushort_t* wt2 = (ushort_t*)p; p += (size_t)R_REL * 64 * 64 * 2;
    ushort_t* rt0 = (ushort_t*)p; p += (size_t)64 * K1 * 2;
    ushort_t* rt1 = (ushort_t*)p; p += (size_t)64 * 64 * 2;
    ushort_t* rt2 = (ushort_t*)p; p += (size_t)64 * 64 * 2;
    int*   offs    = (int*)p;     p += (size_t)N * 4;
    int*   deg     = (int*)p;     p += (size_t)N * 4;
    int*   cursor  = (int*)p;     p += (size_t)N * 4;
    int*   packed  = (int*)p;     p += (size_t)E * 4;
    float* pw      = (float*)p;   p += (size_t)E * 4;
    int*   partials = (int*)p;

    const ushort_t* wt[3] = {wt0, wt1, wt2};
    const ushort_t* rt[3] = {rt0, rt1, rt2};

    const int gxN = (N + 255) / 256;

    // ---- weight + input conversion ----
    wcvt_kernel<<<(R_REL * K1 * 64 + 255) / 256, 256, 0, stream>>>(W[0], wt0, R_REL, K1);
    wcvt_kernel<<<(R_REL * 64 * 64 + 255) / 256, 256, 0, stream>>>(W[1], wt1, R_REL, 64);
    wcvt_kernel<<<(R_REL * 64 * 64 + 255) / 256, 256, 0, stream>>>(W[2], wt2, R_REL, 64);
    wcvt_kernel<<<(K1 * 64 + 255) / 256, 256, 0, stream>>>(root[0], rt0, 1, K1);
    wcvt_kernel<<<(64 * 64 + 255) / 256, 256, 0, stream>>>(root[1], rt1, 1, 64);
    wcvt_kernel<<<(64 * 64 + 255) / 256, 256, 0, stream>>>(root[2], rt2, 1, 64);
    xcvt_kernel<<<((N * K1 / 4) + 255) / 256, 256, 0, stream>>>(x, x16, N * K1 / 4);

    // ---- CSR build ----
    hipMemsetAsync(inv, 0, (size_t)N * R_REL * 4, stream);
    hipMemsetAsync(cursor, 0, (size_t)N * 4, stream);
    count_kernel<<<(E + 255) / 256, 256, 0, stream>>>(ei, et, (int*)inv, E);
    invdeg_kernel<<<gxN, 256, 0, stream>>>(inv, deg, N);
    scan1_kernel<<<gxN, 256, 0, stream>>>(deg, offs, partials, N);
    scan2_kernel<<<1, 256, 0, stream>>>(partials, gxN);
    scan3_kernel<<<gxN, 256, 0, stream>>>(offs, partials, N);
    fill2_kernel<<<(E + 255) / 256, 256, 0, stream>>>(ei, et, offs, cursor, inv, packed, pw, E);

    // ---- 3 RGCN layers ----
    const int gx = (N + 63) / 64;
    const int gagg = (N * 64 + 255) / 256;
    const ushort_t* cur = x16;
    for (int layer = 0; layer < 3; ++layer) {
        const int K = (layer == 0) ? K1 : 64;
        mgemm_kernel<<<dim3(gx, R_REL + 1), 256, 0, stream>>>(
            cur, N, K, wt[layer], rt[layer], bias[layer], Hbuf, accb);
        agg2_kernel<<<gagg, 256, 0, stream>>>(
            packed, pw, offs, deg, Hbuf, accb,
            gamma[layer], beta[layer], rm[layer], rv[layer], xb, N);
        cur = xb;
    }

    lin_kernel<<<(N * 16 + 255) / 256, 256, 0, stream>>>(cur, Wl, bl, (float*)d_out, N);
}

// Round 7
// 396.520 us; speedup vs baseline: 2.4733x; 1.4261x over previous
//
#include <hip/hip_runtime.h>

// ---------------------------------------------------------------------------
// HeteroRGCN: 3x (RGCNConv mean-per-relation + ReLU + BN(eval)) + Linear
// Round 6: agg rewritten as 4-edge-in-flight subgroup gather (uint2/lane,
// 16-lane subgroups, shfl_xor reduce) + int2 edge records. mgemm unchanged.
// ---------------------------------------------------------------------------

#define R_REL 8

typedef unsigned short ushort_t;
typedef short short8 __attribute__((ext_vector_type(8)));
typedef float f32x4 __attribute__((ext_vector_type(4)));

#define MFMA(a, b, c) __builtin_amdgcn_mfma_f32_16x16x32_bf16(a, b, c, 0, 0, 0)

static __device__ __forceinline__ unsigned short f2bf(float f) {
    unsigned int u = __float_as_uint(f);
    u = (u + 0x7FFF + ((u >> 16) & 1)) >> 16;   // round-to-nearest-even
    return (unsigned short)u;
}
static __device__ __forceinline__ float bf2f(unsigned short h) {
    return __uint_as_float(((unsigned int)h) << 16);
}

// ---- weight convert + transpose: src f32 [G][K][64] -> dst bf16 [G][64][K]
__global__ void wcvt_kernel(const float* __restrict__ src, ushort_t* __restrict__ dst,
                            int G, int K)
{
    int i = blockIdx.x * 256 + threadIdx.x;
    if (i >= G * K * 64) return;
    int g = i / (K * 64), rem = i % (K * 64), k = rem >> 6, c = rem & 63;
    dst[(size_t)g * 64 * K + (size_t)c * K + k] = f2bf(src[i]);
}

// ---- input convert: f32 -> bf16 (4 elems/thread)
__global__ void xcvt_kernel(const float* __restrict__ src, ushort_t* __restrict__ dst, int n4)
{
    int i = blockIdx.x * 256 + threadIdx.x;
    if (i >= n4) return;
    float4 v = ((const float4*)src)[i];
    ushort_t t[4] = {f2bf(v.x), f2bf(v.y), f2bf(v.z), f2bf(v.w)};
    *(uint2*)&dst[(size_t)i * 4] = *(const uint2*)t;
}

// ---- MFMA GEMM: A [n x K] bf16 row-major; blockIdx.y<8: B=WT[y] ([64][K] bf16,
// pre-transposed) -> H bf16 (ld 512, colbase y*64); y==8: B=RT -> accb f32 + bias.
__global__ __launch_bounds__(256)
void mgemm_kernel(const ushort_t* __restrict__ A, int n, int K,
                  const ushort_t* __restrict__ WT, const ushort_t* __restrict__ RT,
                  const float* __restrict__ bias,
                  ushort_t* __restrict__ H, float* __restrict__ accb)
{
    __shared__ ushort_t As[64][136];
    __shared__ ushort_t Bs[64][136];

    const int row0 = blockIdx.x * 64;
    const int yr = blockIdx.y;
    const ushort_t* Bsrc = (yr < R_REL) ? (WT + (size_t)yr * 64 * K) : RT;

    const int tid = threadIdx.x;
    const int KB = K >> 3;

    for (int i = tid; i < 64 * KB; i += 256) {
        int r = i / KB, k8 = (i % KB) << 3;
        *(uint4*)&Bs[r][k8] = *(const uint4*)&Bsrc[(size_t)r * K + k8];
        uint4 av = make_uint4(0u, 0u, 0u, 0u);
        if (row0 + r < n) av = *(const uint4*)&A[(size_t)(row0 + r) * K + k8];
        *(uint4*)&As[r][k8] = av;
    }
    __syncthreads();

    const int wid  = tid >> 6;
    const int lane = tid & 63;
    const int wr = (wid >> 1) * 32;
    const int wc = (wid & 1) * 32;
    const int fr = lane & 15;
    const int kg = (lane >> 4) << 3;

    f32x4 acc[2][2] = {};
    for (int k0 = 0; k0 < K; k0 += 32) {
        short8 a0 = *(const short8*)&As[wr + fr     ][k0 + kg];
        short8 a1 = *(const short8*)&As[wr + 16 + fr][k0 + kg];
        short8 b0 = *(const short8*)&Bs[wc + fr     ][k0 + kg];
        short8 b1 = *(const short8*)&Bs[wc + 16 + fr][k0 + kg];
        acc[0][0] = MFMA(a0, b0, acc[0][0]);
        acc[0][1] = MFMA(a0, b1, acc[0][1]);
        acc[1][0] = MFMA(a1, b0, acc[1][0]);
        acc[1][1] = MFMA(a1, b1, acc[1][1]);
    }
    __syncthreads();

    float* Ct = (float*)As;            // [64][68] f32
    const int rbase = (lane >> 4) << 2;
    #pragma unroll
    for (int m = 0; m < 2; ++m)
        #pragma unroll
        for (int nn = 0; nn < 2; ++nn)
            #pragma unroll
            for (int j = 0; j < 4; ++j)
                Ct[(wr + m * 16 + rbase + j) * 68 + wc + nn * 16 + fr] = acc[m][nn][j];
    __syncthreads();

    if (yr < R_REL) {
        const int cb = yr << 6;
        for (int i = tid; i < 64 * 8; i += 256) {
            int r = i >> 3, c8 = (i & 7) << 3;
            if (row0 + r < n) {
                ushort_t t[8];
                #pragma unroll
                for (int j = 0; j < 8; ++j) t[j] = f2bf(Ct[r * 68 + c8 + j]);
                *(uint4*)&H[(size_t)(row0 + r) * 512 + cb + c8] = *(const uint4*)t;
            }
        }
    } else {
        for (int i = tid; i < 64 * 16; i += 256) {
            int r = i >> 4, c4 = (i & 15) << 2;
            if (row0 + r < n) {
                float4 o;
                o.x = Ct[r * 68 + c4 + 0] + bias[c4 + 0];
                o.y = Ct[r * 68 + c4 + 1] + bias[c4 + 1];
                o.z = Ct[r * 68 + c4 + 2] + bias[c4 + 2];
                o.w = Ct[r * 68 + c4 + 3] + bias[c4 + 3];
                *(float4*)&accb[(size_t)(row0 + r) * 64 + c4] = o;
            }
        }
    }
}

// ---- CSR build -------------------------------------------------------------
__global__ void count_kernel(const int* __restrict__ ei, const int* __restrict__ et,
                             int* __restrict__ cnt, int E)
{
    int e = blockIdx.x * 256 + threadIdx.x;
    if (e < E) atomicAdd(&cnt[(size_t)ei[E + e] * R_REL + et[e]], 1);
}

__global__ void invdeg_kernel(float* __restrict__ inv, int* __restrict__ deg, int N)
{
    int i = blockIdx.x * 256 + threadIdx.x;
    if (i >= N) return;
    const int* c = (const int*)inv;
    int tot = 0;
    float out[R_REL];
    #pragma unroll
    for (int r = 0; r < R_REL; ++r) {
        int cc = c[i * R_REL + r];
        tot += cc;
        out[r] = 1.0f / (float)(cc > 1 ? cc : 1);
    }
    #pragma unroll
    for (int r = 0; r < R_REL; ++r) inv[i * R_REL + r] = out[r];
    deg[i] = tot;
}

__global__ void scan1_kernel(const int* __restrict__ deg, int* __restrict__ offs,
                             int* __restrict__ partials, int N)
{
    __shared__ int sm[256];
    int i = blockIdx.x * 256 + threadIdx.x;
    int c = (i < N) ? deg[i] : 0;
    sm[threadIdx.x] = c;
    __syncthreads();
    for (int off = 1; off < 256; off <<= 1) {
        int t = (threadIdx.x >= off) ? sm[threadIdx.x - off] : 0;
        __syncthreads();
        sm[threadIdx.x] += t;
        __syncthreads();
    }
    if (i < N) offs[i] = sm[threadIdx.x] - c;
    if (threadIdx.x == 255) partials[blockIdx.x] = sm[255];
}

__global__ void scan2_kernel(int* __restrict__ partials, int P)
{
    __shared__ int sm[256];
    __shared__ int carry;
    if (threadIdx.x == 0) carry = 0;
    __syncthreads();
    for (int base = 0; base < P; base += 256) {
        int i = base + threadIdx.x;
        int c = (i < P) ? partials[i] : 0;
        sm[threadIdx.x] = c;
        __syncthreads();
        for (int off = 1; off < 256; off <<= 1) {
            int t = (threadIdx.x >= off) ? sm[threadIdx.x - off] : 0;
            __syncthreads();
            sm[threadIdx.x] += t;
            __syncthreads();
        }
        int incl = sm[threadIdx.x];
        int cold = carry;
        if (i < P) partials[i] = incl - c + cold;
        __syncthreads();
        if (threadIdx.x == 0) carry = cold + sm[255];
        __syncthreads();
    }
}

__global__ void scan3_kernel(int* __restrict__ offs, const int* __restrict__ partials, int N)
{
    int i = blockIdx.x * 256 + threadIdx.x;
    if (i < N) offs[i] += partials[blockIdx.x];
}

// scatter: ep[pos] = {src*512 + r*64, bits(1/cnt(dst,rel))}
__global__ void fill3_kernel(const int* __restrict__ ei, const int* __restrict__ et,
                             const int* __restrict__ offs, int* __restrict__ cursor,
                             const float* __restrict__ inv,
                             int2* __restrict__ ep, int E)
{
    int e = blockIdx.x * 256 + threadIdx.x;
    if (e >= E) return;
    int d = ei[E + e];
    int r = et[e];
    int pos = offs[d] + atomicAdd(&cursor[d], 1);
    ep[pos] = make_int2(ei[e] * 512 + r * 64,
                        __float_as_int(inv[(size_t)d * R_REL + r]));
}

// ---- one wave per dst, 4 edges in flight (16-lane subgroups, uint2/lane),
// shfl_xor reduce, fused ReLU+BN -> xout (bf16)
__global__ __launch_bounds__(256)
void agg3_kernel(const int2* __restrict__ ep,
                 const int* __restrict__ offs, const int* __restrict__ deg,
                 const ushort_t* __restrict__ H, const float* __restrict__ accb,
                 const float* __restrict__ g, const float* __restrict__ b,
                 const float* __restrict__ rm, const float* __restrict__ rv,
                 ushort_t* __restrict__ xout, int N)
{
    const int lane = threadIdx.x & 63;
    const int d = (blockIdx.x * 256 + threadIdx.x) >> 6;
    if (d >= N) return;

    const int sub = lane >> 4;        // which edge of the group of 4
    const int fl  = lane & 15;        // feature quad: features 4*fl..4*fl+3
    const int n0 = offs[d];
    const int dg = deg[d];

    float s0 = 0.f, s1 = 0.f, s2 = 0.f, s3 = 0.f;
    int k = 0;

    // 8 edges in flight (2 independent groups of 4)
    for (; k + 8 <= dg; k += 8) {
        int2 eA = ep[n0 + k + sub];
        int2 eB = ep[n0 + k + 4 + sub];
        uint2 hA = *(const uint2*)&H[(size_t)eA.x + (fl << 2)];
        uint2 hB = *(const uint2*)&H[(size_t)eB.x + (fl << 2)];
        float wA = __int_as_float(eA.y);
        float wB = __int_as_float(eB.y);
        s0 += bf2f((ushort_t)(hA.x & 0xFFFF)) * wA + bf2f((ushort_t)(hB.x & 0xFFFF)) * wB;
        s1 += bf2f((ushort_t)(hA.x >> 16))    * wA + bf2f((ushort_t)(hB.x >> 16))    * wB;
        s2 += bf2f((ushort_t)(hA.y & 0xFFFF)) * wA + bf2f((ushort_t)(hB.y & 0xFFFF)) * wB;
        s3 += bf2f((ushort_t)(hA.y >> 16))    * wA + bf2f((ushort_t)(hB.y >> 16))    * wB;
    }
    for (; k + 4 <= dg; k += 4) {
        int2 eA = ep[n0 + k + sub];
        uint2 hA = *(const uint2*)&H[(size_t)eA.x + (fl << 2)];
        float wA = __int_as_float(eA.y);
        s0 += bf2f((ushort_t)(hA.x & 0xFFFF)) * wA;
        s1 += bf2f((ushort_t)(hA.x >> 16))    * wA;
        s2 += bf2f((ushort_t)(hA.y & 0xFFFF)) * wA;
        s3 += bf2f((ushort_t)(hA.y >> 16))    * wA;
    }
    if (k < dg && sub < dg - k) {   // tail: 1..3 edges
        int2 eA = ep[n0 + k + sub];
        uint2 hA = *(const uint2*)&H[(size_t)eA.x + (fl << 2)];
        float wA = __int_as_float(eA.y);
        s0 += bf2f((ushort_t)(hA.x & 0xFFFF)) * wA;
        s1 += bf2f((ushort_t)(hA.x >> 16))    * wA;
        s2 += bf2f((ushort_t)(hA.y & 0xFFFF)) * wA;
        s3 += bf2f((ushort_t)(hA.y >> 16))    * wA;
    }

    // reduce across the 4 subgroups (lanes xor 16, xor 32)
    s0 += __shfl_xor(s0, 16); s1 += __shfl_xor(s1, 16);
    s2 += __shfl_xor(s2, 16); s3 += __shfl_xor(s3, 16);
    s0 += __shfl_xor(s0, 32); s1 += __shfl_xor(s1, 32);
    s2 += __shfl_xor(s2, 32); s3 += __shfl_xor(s3, 32);

    if (sub == 0) {
        const int c4 = fl << 2;
        float4 a  = *(const float4*)&accb[(size_t)d * 64 + c4];
        float4 gm = *(const float4*)&g[c4];
        float4 bt = *(const float4*)&b[c4];
        float4 mu = *(const float4*)&rm[c4];
        float4 vr = *(const float4*)&rv[c4];
        float t0 = a.x + s0, t1 = a.y + s1, t2 = a.z + s2, t3 = a.w + s3;
        t0 = t0 > 0.f ? t0 : 0.f;  t1 = t1 > 0.f ? t1 : 0.f;
        t2 = t2 > 0.f ? t2 : 0.f;  t3 = t3 > 0.f ? t3 : 0.f;
        t0 = (t0 - mu.x) * rsqrtf(vr.x + 1e-5f) * gm.x + bt.x;
        t1 = (t1 - mu.y) * rsqrtf(vr.y + 1e-5f) * gm.y + bt.y;
        t2 = (t2 - mu.z) * rsqrtf(vr.z + 1e-5f) * gm.z + bt.z;
        t3 = (t3 - mu.w) * rsqrtf(vr.w + 1e-5f) * gm.w + bt.w;
        ushort_t o[4] = {f2bf(t0), f2bf(t1), f2bf(t2), f2bf(t3)};
        *(uint2*)&xout[(size_t)d * 64 + c4] = *(const uint2*)o;
    }
}

// ---- final linear: out[n][c] = sum_k h[n][k]*Wl[k][c] + bl[c]   (C=16)
__global__ __launch_bounds__(256)
void lin_kernel(const ushort_t* __restrict__ h, const float* __restrict__ Wl,
                const float* __restrict__ bl, float* __restrict__ out, int N)
{
    __shared__ float w[64 * 16];
    __shared__ float bb[16];
    for (int i = threadIdx.x; i < 64 * 16; i += 256) w[i] = Wl[i];
    if (threadIdx.x < 16) bb[threadIdx.x] = bl[threadIdx.x];
    __syncthreads();

    int idx = blockIdx.x * 256 + threadIdx.x;
    if (idx >= N * 16) return;
    int node = idx >> 4, c = idx & 15;
    float s = bb[c];
    const ushort_t* hr = h + (size_t)node * 64;
    #pragma unroll 16
    for (int k = 0; k < 64; ++k) s += bf2f(hr[k]) * w[k * 16 + c];
    out[idx] = s;
}

extern "C" void kernel_launch(void* const* d_in, const int* in_sizes, int n_in,
                              void* d_out, int out_size, void* d_ws, size_t ws_size,
                              hipStream_t stream)
{
    const float* x  = (const float*)d_in[0];
    const int*   ei = (const int*)d_in[1];
    const int*   et = (const int*)d_in[2];
    const float* W[3]    = {(const float*)d_in[3], (const float*)d_in[6], (const float*)d_in[9]};
    const float* root[3] = {(const float*)d_in[4], (const float*)d_in[7], (const float*)d_in[10]};
    const float* bias[3] = {(const float*)d_in[5], (const float*)d_in[8], (const float*)d_in[11]};
    const float* gamma[3] = {(const float*)d_in[12], (const float*)d_in[16], (const float*)d_in[20]};
    const float* beta[3]  = {(const float*)d_in[13], (const float*)d_in[17], (const float*)d_in[21]};
    const float* rm[3]    = {(const float*)d_in[14], (const float*)d_in[18], (const float*)d_in[22]};
    const float* rv[3]    = {(const float*)d_in[15], (const float*)d_in[19], (const float*)d_in[23]};
    const float* Wl = (const float*)d_in[24];
    const float* bl = (const float*)d_in[25];

    const int N = in_sizes[0] / 128;
    const int E = in_sizes[2];
    const int K1 = 128;

    // ---- workspace layout (all 16B aligned) ----
    char* p = (char*)d_ws;
    float*   inv  = (float*)p;    p += (size_t)N * R_REL * 4;
    ushort_t* Hbuf = (ushort_t*)p; p += (size_t)N * 512 * 2;
    float*   accb = (float*)p;    p += (size_t)N * 64 * 4;
    ushort_t* xb  = (ushort_t*)p; p += (size_t)N * 64 * 2;
    ushort_t* x16 = (ushort_t*)p; p += (size_t)N * K1 * 2;
    ushort_t* wt0 = (ushort_t*)p; p += (size_t)R_REL * 64 * K1 * 2;
    ushort_t* wt1 = (ushort_t*)p; p += (size_t)R_REL * 64 * 64 * 2;
    ushort_t* wt2 = (ushort_t*)p; p += (size_t)R_REL * 64 * 64 * 2;
    ushort_t* rt0 = (ushort_t*)p; p += (size_t)64 * K1 * 2;
    ushort_t* rt1 = (ushort_t*)p; p += (size_t)64 * 64 * 2;
    ushort_t* rt2 = (ushort_t*)p; p += (size_t)64 * 64 * 2;
    int*   offs    = (int*)p;     p += (size_t)N * 4;
    int*   deg     = (int*)p;     p += (size_t)N * 4;
    int*   cursor  = (int*)p;     p += (size_t)N * 4;
    int2*  ep      = (int2*)p;    p += (size_t)E * 8;
    int*   partials = (int*)p;

    const ushort_t* wt[3] = {wt0, wt1, wt2};
    const ushort_t* rt[3] = {rt0, rt1, rt2};

    const int gxN = (N + 255) / 256;

    // ---- weight + input conversion ----
    wcvt_kernel<<<(R_REL * K1 * 64 + 255) / 256, 256, 0, stream>>>(W[0], wt0, R_REL, K1);
    wcvt_kernel<<<(R_REL * 64 * 64 + 255) / 256, 256, 0, stream>>>(W[1], wt1, R_REL, 64);
    wcvt_kernel<<<(R_REL * 64 * 64 + 255) / 256, 256, 0, stream>>>(W[2], wt2, R_REL, 64);
    wcvt_kernel<<<(K1 * 64 + 255) / 256, 256, 0, stream>>>(root[0], rt0, 1, K1);
    wcvt_kernel<<<(64 * 64 + 255) / 256, 256, 0, stream>>>(root[1], rt1, 1, 64);
    wcvt_kernel<<<(64 * 64 + 255) / 256, 256, 0, stream>>>(root[2], rt2, 1, 64);
    xcvt_kernel<<<((N * K1 / 4) + 255) / 256, 256, 0, stream>>>(x, x16, N * K1 / 4);

    // ---- CSR build ----
    hipMemsetAsync(inv, 0, (size_t)N * R_REL * 4, stream);
    hipMemsetAsync(cursor, 0, (size_t)N * 4, stream);
    count_kernel<<<(E + 255) / 256, 256, 0, stream>>>(ei, et, (int*)inv, E);
    invdeg_kernel<<<gxN, 256, 0, stream>>>(inv, deg, N);
    scan1_kernel<<<gxN, 256, 0, stream>>>(deg, offs, partials, N);
    scan2_kernel<<<1, 256, 0, stream>>>(partials, gxN);
    scan3_kernel<<<gxN, 256, 0, stream>>>(offs, partials, N);
    fill3_kernel<<<(E + 255) / 256, 256, 0, stream>>>(ei, et, offs, cursor, inv, ep, E);

    // ---- 3 RGCN layers ----
    const int gx = (N + 63) / 64;
    const int gagg = (N * 64 + 255) / 256;
    const ushort_t* cur = x16;
    for (int layer = 0; layer < 3; ++layer) {
        const int K = (layer == 0) ? K1 : 64;
        mgemm_kernel<<<dim3(gx, R_REL + 1), 256, 0, stream>>>(
            cur, N, K, wt[layer], rt[layer], bias[layer], Hbuf, accb);
        agg3_kernel<<<gagg, 256, 0, stream>>>(
            ep, offs, deg, Hbuf, accb,
            gamma[layer], beta[layer], rm[layer], rv[layer], xb, N);
        cur = xb;
    }

    lin_kernel<<<(N * 16 + 255) / 256, 256, 0, stream>>>(cur, Wl, bl, (float*)d_out, N);
}